// Round 1
// 430.995 us; speedup vs baseline: 1.0429x; 1.0429x over previous
//
#include <hip/hip_runtime.h>
#include <hip/hip_bf16.h>
#include <stdint.h>

typedef __attribute__((ext_vector_type(8))) short short8;
typedef __attribute__((ext_vector_type(4))) float floatx4;

#define N_NODES 4096
#define CDIM 64
#define HDIM 128

#define AS1 __attribute__((address_space(1)))
#define AS3 __attribute__((address_space(3)))

__device__ __forceinline__ void gload_lds16(const void* g, void* l) {
    __builtin_amdgcn_global_load_lds((const AS1 void*)g, (AS3 void*)l, 16, 0, 0);
}

// -------- kernel 1: fused rowsum + A passthrough copy + bf16 convert --------
// dvec[row] = rsqrt(rowsum(A)+1); outA = A; Ab = bf16(A). One read of A.
__global__ __launch_bounds__(256) void k_prep(const float* __restrict__ A,
                                              float* __restrict__ outA,
                                              __hip_bfloat16* __restrict__ Ab,
                                              float* __restrict__ dvec) {
    const int row = blockIdx.x;
    const int t = threadIdx.x;
    const float4* Ar = (const float4*)(A + (size_t)row * N_NODES);
    float4* Or = (float4*)(outA + (size_t)row * N_NODES);
    short4* Br = (short4*)(Ab + (size_t)row * N_NODES);
    float s = 0.f;
    #pragma unroll
    for (int j = 0; j < 4; ++j) {
        int q = t + j * 256;
        float4 v = Ar[q];
        Or[q] = v;
        union { __hip_bfloat16 h[4]; short4 s4; } u;
        u.h[0] = __float2bfloat16(v.x);
        u.h[1] = __float2bfloat16(v.y);
        u.h[2] = __float2bfloat16(v.z);
        u.h[3] = __float2bfloat16(v.w);
        Br[q] = u.s4;
        s += v.x + v.y + v.z + v.w;
    }
    #pragma unroll
    for (int off = 32; off > 0; off >>= 1) s += __shfl_down(s, off, 64);
    __shared__ float ps[4];
    if ((t & 63) == 0) ps[t >> 6] = s;
    __syncthreads();
    if (t == 0) {
        float tot = ps[0] + ps[1] + ps[2] + ps[3];
        dvec[row] = rsqrtf(tot + 1.0f);
    }
}

// ------ kernel 2: Xt[(bs*64+c)][k] = bf16(d[k] * x[bs,k,c])  (K-major) ------
__global__ __launch_bounds__(256) void k_buildXt(const float* __restrict__ x,
                                                 const float* __restrict__ dvec,
                                                 __hip_bfloat16* __restrict__ Xt) {
    __shared__ float tile[64 * 65];
    __shared__ float dloc[64];
    const int t = threadIdx.x;
    const int bs = blockIdx.y;
    const int k0 = blockIdx.x * 64;
    const float* xp = x + ((size_t)bs * N_NODES + k0) * CDIM;
    const float4* xp4 = (const float4*)xp;
    #pragma unroll
    for (int it = 0; it < 4; ++it) {
        int q = it * 256 + t;
        float4 v = xp4[q];
        int p = q * 4;
        int kk = p >> 6, c = p & 63;
        tile[kk * 65 + c + 0] = v.x;
        tile[kk * 65 + c + 1] = v.y;
        tile[kk * 65 + c + 2] = v.z;
        tile[kk * 65 + c + 3] = v.w;
    }
    if (t < 64) dloc[t] = dvec[k0 + t];
    __syncthreads();
    #pragma unroll
    for (int it = 0; it < 16; ++it) {
        int p = it * 256 + t;
        int c = p >> 6;
        int kk = p & 63;
        float v = tile[kk * 65 + c] * dloc[kk];
        Xt[(size_t)(bs * CDIM + c) * N_NODES + k0 + kk] = __float2bfloat16(v);
    }
}

// ------ kernel 3 (fused): Z = Ab·Xt^T; G = x - d*Z (LDS); out = sigmoid(G·W^T) ------
// Main loop: explicit double-buffered LDS (T3 minimum-2-phase):
//   STAGE(next tile) issued BEFORE ds_read+MFMA of current tile; ONE barrier/iter.
//   The barrier's implicit vmcnt(0) then lands after ~fragment-read+MFMA-issue time
//   instead of immediately after load issue, hiding L2/L3 latency within the block.
__global__ __launch_bounds__(256) void k_gemm_out(const __hip_bfloat16* __restrict__ Ab,
                                                  const __hip_bfloat16* __restrict__ Xt,
                                                  const float* __restrict__ x,
                                                  const float* __restrict__ dvec,
                                                  const float* __restrict__ W,
                                                  float* __restrict__ out) {
    // smem: main loop uses dbuf[2] x {As 8KB, Bs 8KB} = 32KB (stride 16384);
    //       epilogue reuses [0,36864) as Gs [2][128][72] + Wbs 16KB @ +36864
    __shared__ __align__(16) char smem[53248];
    __hip_bfloat16* Gs  = (__hip_bfloat16*)smem;            // [2][128][72]
    __hip_bfloat16* Wbs = (__hip_bfloat16*)(smem + 36864);  // [128][64]

    const int t = threadIdx.x;
    const int w = t >> 6, l = t & 63;
    const int i0 = blockIdx.y * 128;
    const int j0 = blockIdx.x * 128;
    const int wm = w >> 1, wn = w & 1;
    const int ar = l & 15;
    const int kq = (l >> 4) * 8;
    const int col = l & 15;
    const int rowq = (l >> 4) * 4;

    const int srow = t >> 2;
    const int skcol = (t & 3) * 8;

    // stage W into LDS as bf16 [h][c] (Wbs doesn't alias the dbuf; done once)
    {
        const float4* W4 = (const float4*)W;   // 2048 float4
        #pragma unroll
        for (int it = 0; it < 8; ++it) {
            int q4 = it * 256 + t;
            float4 v = W4[q4];
            int p = q4 * 4;          // = h*64 + c, c%4==0
            union { __hip_bfloat16 h[4]; short4 s4; } u;
            u.h[0] = __float2bfloat16(v.x);
            u.h[1] = __float2bfloat16(v.y);
            u.h[2] = __float2bfloat16(v.z);
            u.h[3] = __float2bfloat16(v.w);
            *(short4*)(Wbs + p) = u.s4;
        }
    }

    floatx4 acc[4][4];
    #pragma unroll
    for (int a = 0; a < 4; ++a)
        #pragma unroll
        for (int b = 0; b < 4; ++b)
            acc[a][b] = (floatx4){0.f, 0.f, 0.f, 0.f};

    const __hip_bfloat16* gA0 = Ab + (size_t)(i0 + srow) * N_NODES + skcol;
    const __hip_bfloat16* gB0 = Xt + (size_t)(j0 + srow) * N_NODES + skcol;

    // issue the 4 global->LDS loads of one 32-wide K-tile into buffer `buf`
    auto stage = [&](int buf, int kk) {
        __hip_bfloat16* As = (__hip_bfloat16*)(smem + buf * 16384);
        __hip_bfloat16* Bs = As + 4096;   // +8192 bytes
        gload_lds16(gA0 + kk,                        As + w * 512);
        gload_lds16(gA0 + (size_t)64 * N_NODES + kk, As + 2048 + w * 512);
        gload_lds16(gB0 + kk,                        Bs + w * 512);
        gload_lds16(gB0 + (size_t)64 * N_NODES + kk, Bs + 2048 + w * 512);
    };

    // prologue: fill buffer 0, drain, barrier
    stage(0, 0);
    __syncthreads();

    int cur = 0;
    for (int k0 = 0; k0 < N_NODES; k0 += 32) {
        const int nxt = cur ^ 1;
        if (k0 + 32 < N_NODES) stage(nxt, k0 + 32);   // loads fly during compute below

        const __hip_bfloat16* As = (const __hip_bfloat16*)(smem + cur * 16384);
        const __hip_bfloat16* Bs = As + 4096;
        short8 af[4], bfr[4];
        #pragma unroll
        for (int mt = 0; mt < 4; ++mt)
            af[mt] = *(const short8*)(As + (wm * 64 + mt * 16 + ar) * 32 + kq);
        #pragma unroll
        for (int nt = 0; nt < 4; ++nt)
            bfr[nt] = *(const short8*)(Bs + (wn * 64 + nt * 16 + ar) * 32 + kq);
        #pragma unroll
        for (int mt = 0; mt < 4; ++mt)
            #pragma unroll
            for (int nt = 0; nt < 4; ++nt)
                acc[mt][nt] = __builtin_amdgcn_mfma_f32_16x16x32_bf16(
                    af[mt], bfr[nt], acc[mt][nt], 0, 0, 0);

        __syncthreads();   // implicit vmcnt(0): next buffer complete; lgkm drained
        cur = nxt;
    }

    // ---- epilogue stage 1: G = bf16(x - d*Z) into Gs (overwrites dbuf) ----
    __syncthreads();
    #pragma unroll
    for (int mt = 0; mt < 4; ++mt) {
        const int irel_base = wm * 64 + mt * 16 + rowq;
        #pragma unroll
        for (int nt = 0; nt < 4; ++nt) {
            const int jj = wn * 64 + nt * 16 + col;    // 0..127
            const int bsr = jj >> 6, c = jj & 63;
            const int bs_abs = blockIdx.x * 2 + bsr;
            #pragma unroll
            for (int r = 0; r < 4; ++r) {
                const int irel = irel_base + r;
                const int i = i0 + irel;
                const size_t xi = ((size_t)bs_abs * N_NODES + i) * CDIM + c;
                float g = x[xi] - dvec[i] * acc[mt][nt][r];
                Gs[bsr * 9216 + irel * 72 + c] = __float2bfloat16(g);
            }
        }
    }
    __syncthreads();

    // ---- epilogue stage 2: out = sigmoid(G · W^T) via MFMA, per bs ----
    #pragma unroll
    for (int bsr = 0; bsr < 2; ++bsr) {
        const int bs_abs = blockIdx.x * 2 + bsr;
        floatx4 o[4][4];
        #pragma unroll
        for (int a = 0; a < 4; ++a)
            #pragma unroll
            for (int b = 0; b < 4; ++b)
                o[a][b] = (floatx4){0.f, 0.f, 0.f, 0.f};
        #pragma unroll
        for (int ks = 0; ks < 2; ++ks) {
            const int kk = ks * 32 + kq;
            short8 gf[4], wf[4];
            #pragma unroll
            for (int mt = 0; mt < 4; ++mt)
                gf[mt] = *(const short8*)(Gs + bsr * 9216 + (wm * 64 + mt * 16 + ar) * 72 + kk);
            #pragma unroll
            for (int nt = 0; nt < 4; ++nt)
                wf[nt] = *(const short8*)(Wbs + (wn * 64 + nt * 16 + ar) * 64 + kk);
            #pragma unroll
            for (int mt = 0; mt < 4; ++mt)
                #pragma unroll
                for (int nt = 0; nt < 4; ++nt)
                    o[mt][nt] = __builtin_amdgcn_mfma_f32_16x16x32_bf16(
                        gf[mt], wf[nt], o[mt][nt], 0, 0, 0);
        }
        #pragma unroll
        for (int mt = 0; mt < 4; ++mt) {
            #pragma unroll
            for (int nt = 0; nt < 4; ++nt) {
                const int h = wn * 64 + nt * 16 + col;
                #pragma unroll
                for (int r = 0; r < 4; ++r) {
                    const int i = i0 + wm * 64 + mt * 16 + rowq + r;
                    float v = 1.f / (1.f + __expf(-o[mt][nt][r]));
                    out[((size_t)bs_abs * N_NODES + i) * HDIM + h] = v;
                }
            }
        }
    }
}

// -------- legacy fallback path (small workspace): gemm->G, then k_out --------
__global__ __launch_bounds__(256) void k_gemm(const __hip_bfloat16* __restrict__ Ab,
                                              const __hip_bfloat16* __restrict__ Xt,
                                              const float* __restrict__ x,
                                              const float* __restrict__ dvec,
                                              __hip_bfloat16* __restrict__ G) {
    __shared__ __hip_bfloat16 As[128 * 32];
    __shared__ __hip_bfloat16 Bs[128 * 32];
    const int t = threadIdx.x;
    const int w = t >> 6, l = t & 63;
    const int i0 = blockIdx.y * 128;
    const int j0 = blockIdx.x * 128;
    const int wm = w >> 1, wn = w & 1;
    const int ar = l & 15;
    const int kq = (l >> 4) * 8;
    const int srow = t >> 2;
    const int skcol = (t & 3) * 8;

    floatx4 acc[4][4];
    #pragma unroll
    for (int a = 0; a < 4; ++a)
        #pragma unroll
        for (int b = 0; b < 4; ++b)
            acc[a][b] = (floatx4){0.f, 0.f, 0.f, 0.f};

    const __hip_bfloat16* gA0 = Ab + (size_t)(i0 + srow) * N_NODES + skcol;
    const __hip_bfloat16* gB0 = Xt + (size_t)(j0 + srow) * N_NODES + skcol;

    for (int k0 = 0; k0 < N_NODES; k0 += 32) {
        __syncthreads();
        gload_lds16(gA0 + k0,                        As + w * 512);
        gload_lds16(gA0 + (size_t)64 * N_NODES + k0, As + 2048 + w * 512);
        gload_lds16(gB0 + k0,                        Bs + w * 512);
        gload_lds16(gB0 + (size_t)64 * N_NODES + k0, Bs + 2048 + w * 512);
        __syncthreads();
        short8 af[4], bfr[4];
        #pragma unroll
        for (int mt = 0; mt < 4; ++mt)
            af[mt] = *(const short8*)(As + (wm * 64 + mt * 16 + ar) * 32 + kq);
        #pragma unroll
        for (int nt = 0; nt < 4; ++nt)
            bfr[nt] = *(const short8*)(Bs + (wn * 64 + nt * 16 + ar) * 32 + kq);
        #pragma unroll
        for (int mt = 0; mt < 4; ++mt)
            #pragma unroll
            for (int nt = 0; nt < 4; ++nt)
                acc[mt][nt] = __builtin_amdgcn_mfma_f32_16x16x32_bf16(
                    af[mt], bfr[nt], acc[mt][nt], 0, 0, 0);
    }

    #pragma unroll
    for (int mt = 0; mt < 4; ++mt) {
        const int ibase = i0 + wm * 64 + mt * 16 + (l >> 4) * 4;
        #pragma unroll
        for (int nt = 0; nt < 4; ++nt) {
            const int j = j0 + wn * 64 + nt * 16 + (l & 15);
            const int bs = j >> 6, c = j & 63;
            #pragma unroll
            for (int r = 0; r < 4; ++r) {
                const int i = ibase + r;
                const size_t xi = ((size_t)bs * N_NODES + i) * CDIM + c;
                float g = x[xi] - dvec[i] * acc[mt][nt][r];
                G[xi] = __float2bfloat16(g);
            }
        }
    }
}

__global__ __launch_bounds__(256) void k_out(const __hip_bfloat16* __restrict__ G,
                                             const float* __restrict__ W,
                                             float* __restrict__ out) {
    __shared__ float Wt[64 * 132];
    __shared__ __hip_bfloat16 Gs[32 * 64];
    const int t = threadIdx.x;
    const int bs = blockIdx.y;
    const int i0 = blockIdx.x * 32;
    #pragma unroll
    for (int it = 0; it < 32; ++it) {
        int p = it * 256 + t;
        int h = p & 127, c = p >> 7;
        Wt[c * 132 + h] = W[h * 64 + c];
    }
    const short4* gp4 = (const short4*)(G + ((size_t)bs * N_NODES + i0) * CDIM);
    ((short4*)Gs)[t]       = gp4[t];
    ((short4*)Gs)[256 + t] = gp4[256 + t];
    __syncthreads();

    const int hg = t & 31;
    const int ig = t >> 5;
    float acc[4][4] = {};
    #pragma unroll
    for (int c = 0; c < 64; ++c) {
        float4 wv = *(const float4*)(Wt + c * 132 + hg * 4);
        #pragma unroll
        for (int ii = 0; ii < 4; ++ii) {
            float g = __bfloat162float(Gs[(ig * 4 + ii) * 64 + c]);
            acc[ii][0] += g * wv.x;
            acc[ii][1] += g * wv.y;
            acc[ii][2] += g * wv.z;
            acc[ii][3] += g * wv.w;
        }
    }
    #pragma unroll
    for (int ii = 0; ii < 4; ++ii) {
        const int i = i0 + ig * 4 + ii;
        float4 o;
        o.x = 1.f / (1.f + __expf(-acc[ii][0]));
        o.y = 1.f / (1.f + __expf(-acc[ii][1]));
        o.z = 1.f / (1.f + __expf(-acc[ii][2]));
        o.w = 1.f / (1.f + __expf(-acc[ii][3]));
        *(float4*)(out + ((size_t)bs * N_NODES + i) * HDIM + hg * 4) = o;
    }
}

extern "C" void kernel_launch(void* const* d_in, const int* in_sizes, int n_in,
                              void* d_out, int out_size, void* d_ws, size_t ws_size,
                              hipStream_t stream) {
    const float* x = (const float*)d_in[0];   // [48][4096][64]
    const float* A = (const float*)d_in[1];   // [4096][4096]
    const float* W = (const float*)d_in[2];   // [128][64]
    float* out  = (float*)d_out;              // out0: 25165824 floats
    float* outA = out + 25165824;             // A passthrough

    char* ws = (char*)d_ws;
    float* dvec = (float*)ws;
    const size_t offD = 16384;
    const size_t szAb = (size_t)16777216 * 2;     // 32 MB
    const size_t szXt = (size_t)3072 * 4096 * 2;  // 24 MB
    const size_t szG  = (size_t)48 * 4096 * 64 * 2;

    if (ws_size >= offD + szAb + szXt) {
        // fused path: Ab, Xt in workspace; no G intermediate
        __hip_bfloat16* Ab = (__hip_bfloat16*)(ws + offD);
        __hip_bfloat16* Xt = (__hip_bfloat16*)(ws + offD + szAb);
        k_prep    <<<4096, 256, 0, stream>>>(A, outA, Ab, dvec);
        k_buildXt <<<dim3(64, 48), 256, 0, stream>>>(x, dvec, Xt);
        k_gemm_out<<<dim3(24, 32), 256, 0, stream>>>(Ab, Xt, x, dvec, W, out);
    } else {
        // legacy fallback: Ab in (dead) out0 region, G in ws
        __hip_bfloat16* Ab = (__hip_bfloat16*)out;
        __hip_bfloat16* Xt = (__hip_bfloat16*)(ws + offD);
        __hip_bfloat16* G  = (__hip_bfloat16*)(ws + offD + szXt);
        k_prep    <<<4096, 256, 0, stream>>>(A, outA, Ab, dvec);
        k_buildXt <<<dim3(64, 48), 256, 0, stream>>>(x, dvec, Xt);
        k_gemm    <<<dim3(24, 32), 256, 0, stream>>>(Ab, Xt, x, dvec, G);
        k_out     <<<dim3(128, 48), 256, 0, stream>>>(G, W, out);
    }
}

// Round 2
// 383.022 us; speedup vs baseline: 1.1735x; 1.1252x over previous
//
#include <hip/hip_runtime.h>
#include <hip/hip_bf16.h>
#include <stdint.h>

typedef __attribute__((ext_vector_type(8))) short short8;
typedef __attribute__((ext_vector_type(4))) float floatx4;

#define N_NODES 4096
#define CDIM 64
#define HDIM 128

#define AS1 __attribute__((address_space(1)))
#define AS3 __attribute__((address_space(3)))

__device__ __forceinline__ void gload_lds16(const void* g, void* l) {
    __builtin_amdgcn_global_load_lds((const AS1 void*)g, (AS3 void*)l, 16, 0, 0);
}

#define SB0 __builtin_amdgcn_sched_barrier(0)
#define BARRIER __builtin_amdgcn_s_barrier()
#define LGKM0 asm volatile("s_waitcnt lgkmcnt(0)" ::: "memory")

// -------- kernel 1: fused rowsum + A passthrough copy + bf16 convert --------
__global__ __launch_bounds__(256) void k_prep(const float* __restrict__ A,
                                              float* __restrict__ outA,
                                              __hip_bfloat16* __restrict__ Ab,
                                              float* __restrict__ dvec) {
    const int row = blockIdx.x;
    const int t = threadIdx.x;
    const float4* Ar = (const float4*)(A + (size_t)row * N_NODES);
    float4* Or = (float4*)(outA + (size_t)row * N_NODES);
    short4* Br = (short4*)(Ab + (size_t)row * N_NODES);
    float s = 0.f;
    #pragma unroll
    for (int j = 0; j < 4; ++j) {
        int q = t + j * 256;
        float4 v = Ar[q];
        Or[q] = v;
        union { __hip_bfloat16 h[4]; short4 s4; } u;
        u.h[0] = __float2bfloat16(v.x);
        u.h[1] = __float2bfloat16(v.y);
        u.h[2] = __float2bfloat16(v.z);
        u.h[3] = __float2bfloat16(v.w);
        Br[q] = u.s4;
        s += v.x + v.y + v.z + v.w;
    }
    #pragma unroll
    for (int off = 32; off > 0; off >>= 1) s += __shfl_down(s, off, 64);
    __shared__ float ps[4];
    if ((t & 63) == 0) ps[t >> 6] = s;
    __syncthreads();
    if (t == 0) {
        float tot = ps[0] + ps[1] + ps[2] + ps[3];
        dvec[row] = rsqrtf(tot + 1.0f);
    }
}

// ------ kernel 2: Xt[(bs*64+c)][k] = bf16(d[k] * x[bs,k,c])  (K-major) ------
__global__ __launch_bounds__(256) void k_buildXt(const float* __restrict__ x,
                                                 const float* __restrict__ dvec,
                                                 __hip_bfloat16* __restrict__ Xt) {
    __shared__ float tile[64 * 65];
    __shared__ float dloc[64];
    const int t = threadIdx.x;
    const int bs = blockIdx.y;
    const int k0 = blockIdx.x * 64;
    const float* xp = x + ((size_t)bs * N_NODES + k0) * CDIM;
    const float4* xp4 = (const float4*)xp;
    #pragma unroll
    for (int it = 0; it < 4; ++it) {
        int q = it * 256 + t;
        float4 v = xp4[q];
        int p = q * 4;
        int kk = p >> 6, c = p & 63;
        tile[kk * 65 + c + 0] = v.x;
        tile[kk * 65 + c + 1] = v.y;
        tile[kk * 65 + c + 2] = v.z;
        tile[kk * 65 + c + 3] = v.w;
    }
    if (t < 64) dloc[t] = dvec[k0 + t];
    __syncthreads();
    #pragma unroll
    for (int it = 0; it < 16; ++it) {
        int p = it * 256 + t;
        int c = p >> 6;
        int kk = p & 63;
        float v = tile[kk * 65 + c] * dloc[kk];
        Xt[(size_t)(bs * CDIM + c) * N_NODES + k0 + kk] = __float2bfloat16(v);
    }
}

// ====== kernel 3: 256x256 8-phase GEMM (T2+T3+T4+T5) + fused epilogue ======
// Z = Ab·Xt^T; G = x - d*Z (LDS, swizzled); out = sigmoid(G·W^T) via MFMA.
// LDS map: [0,131072): dbuf[2] x {A_k0,A_k1,B_k0,B_k1}[256][32] bf16 subtiles
//          (each 16KB, XOR-swizzled byte ^= (row&3)<<4 via pre-swizzled src);
//          epilogue overlays as Gs[4][256][64] (byte ^= (row&7)<<4).
//          [131072,149504): Wbs [128][72] bf16 (padded, no conflicts).
__global__ __launch_bounds__(512, 2) void k_gemm_out(const __hip_bfloat16* __restrict__ Ab,
                                                     const __hip_bfloat16* __restrict__ Xt,
                                                     const float* __restrict__ x,
                                                     const float* __restrict__ dvec,
                                                     const float* __restrict__ W,
                                                     float* __restrict__ out) {
    __shared__ __align__(16) char smem[149504];
    __hip_bfloat16* Wbs = (__hip_bfloat16*)(smem + 131072);

    const int t = threadIdx.x;
    const int w = t >> 6, l = t & 63;
    const int wm = w >> 2, wn = w & 3;          // 2 x 4 wave grid
    const int ar = l & 15;
    const int kq = (l >> 4) * 8;                // k elem offset within 32-half
    const int kqb = kq * 2;                     // bytes: 0,16,32,48
    const int col = l & 15;
    const int rowq = (l >> 4) * 4;
    const int xorR = (ar & 3) << 4;             // read-side swizzle (row&3 == ar&3)

    // XCD-bijective block swizzle (192 blocks, 192%8==0)
    const int flat = blockIdx.x;
    const int tid2 = (flat & 7) * 24 + (flat >> 3);
    const int bx = tid2 % 12;                   // N tiles (3072/256)
    const int by = tid2 / 12;                   // M tiles (4096/256)
    const int i0 = by * 256;
    const int j0 = bx * 256;

    // ---- stage W -> Wbs (padded [128][72]) ----
    {
        const float4* W4 = (const float4*)W;    // 2048 float4
        #pragma unroll
        for (int it = 0; it < 4; ++it) {
            int q4 = it * 512 + t;
            float4 v = W4[q4];
            int p = q4 * 4;                     // h*64 + c, c%4==0
            int h = p >> 6, c = p & 63;
            union { __hip_bfloat16 hh[4]; short4 s4; } u;
            u.hh[0] = __float2bfloat16(v.x);
            u.hh[1] = __float2bfloat16(v.y);
            u.hh[2] = __float2bfloat16(v.z);
            u.hh[3] = __float2bfloat16(v.w);
            *(short4*)(Wbs + h * 72 + c) = u.s4;
        }
    }
    SB0;

    // ---- per-lane pre-swizzled global source for staging ----
    // chunk for lane: row = rd*128 + w*16 + (l>>2), lds_slot = l&3,
    // content = global 16B chunk (l&3)^(row&3) of that row's k-half.
    const int rloc = w * 16 + (l >> 2);
    const int slot = (l & 3) ^ (rloc & 3);
    const __hip_bfloat16* gA = Ab + (size_t)(i0 + rloc) * N_NODES + slot * 8;
    const __hip_bfloat16* gB = Xt + (size_t)(j0 + rloc) * N_NODES + slot * 8;

    // stage one 16KB [256][32] subtile of K-tile `tile`, k-half kk
    auto stage = [&](const __hip_bfloat16* gbase, int buf, int subByte, int tile, int kk) {
        const __hip_bfloat16* g = gbase + tile * 64 + kk * 32;
        char* d = smem + buf * 65536 + subByte + w * 1024;
        gload_lds16(g, d);                           // rows rloc (rd=0)
        gload_lds16(g + (size_t)128 * N_NODES, d + 8192);  // rows rloc+128 (rd=1)
    };

    floatx4 acc[8][4];
    #pragma unroll
    for (int a = 0; a < 8; ++a)
        #pragma unroll
        for (int b = 0; b < 4; ++b)
            acc[a][b] = (floatx4){0.f, 0.f, 0.f, 0.f};

    // fragment readers (swizzled)
    auto ldA = [&](short8* dst, int buf, int kk, int mh) {
        const char* base = smem + buf * 65536 + kk * 16384;
        const int off = (wm * 128 + mh * 64 + ar) * 64 + (kqb ^ xorR);
        #pragma unroll
        for (int mt = 0; mt < 4; ++mt)
            dst[mt] = *(const short8*)(base + off + mt * 1024);
    };
    auto ldB = [&](short8* dst, int buf, int kk) {
        const char* base = smem + buf * 65536 + 32768 + kk * 16384;
        const int off = (wn * 64 + ar) * 64 + (kqb ^ xorR);
        #pragma unroll
        for (int nt = 0; nt < 4; ++nt)
            dst[nt] = *(const short8*)(base + off + nt * 1024);
    };
    auto mm16 = [&](const short8* a, const short8* b, int mh) {
        #pragma unroll
        for (int mt = 0; mt < 4; ++mt)
            #pragma unroll
            for (int nt = 0; nt < 4; ++nt)
                acc[mh * 4 + mt][nt] = __builtin_amdgcn_mfma_f32_16x16x32_bf16(
                    a[mt], b[nt], acc[mh * 4 + mt][nt], 0, 0, 0);
    };

    // ---- prologue: tile0 (4 subtiles) + tile1 (3 subtiles); wait oldest 8 ----
    stage(gA, 0, 0,     0, 0);   // A_k0(0)
    stage(gB, 0, 32768, 0, 0);   // B_k0(0)
    stage(gA, 0, 16384, 0, 1);   // A_k1(0)
    stage(gB, 0, 49152, 0, 1);   // B_k1(0)
    stage(gB, 1, 32768, 1, 0);   // B_k0(1)
    stage(gA, 1, 0,     1, 0);   // A_k0(1)
    stage(gB, 1, 49152, 1, 1);   // B_k1(1)
    asm volatile("s_waitcnt vmcnt(6)" ::: "memory");
    BARRIER;

    // ---- main loop: 64 K-tiles, 4 phases each ----
    #pragma unroll 2
    for (int tt = 0; tt < 64; ++tt) {
        const int buf = tt & 1;
        short8 a4[4], b4[4];

        // phase 0: kk=0, mh=0 (reads A_k0 lower + all B_k0); stage A_k1(t+1)
        SB0;
        ldA(a4, buf, 0, 0); ldB(b4, buf, 0);
        SB0;
        if (tt + 1 < 64) stage(gA, buf ^ 1, 16384, tt + 1, 1);
        BARRIER; LGKM0; SB0;
        __builtin_amdgcn_s_setprio(1);
        mm16(a4, b4, 0);
        __builtin_amdgcn_s_setprio(0);
        BARRIER;

        // phase 1: kk=0, mh=1 (A_k0 upper; B regs reused); stage B_k0(t+2)
        SB0;
        ldA(a4, buf, 0, 1);
        SB0;
        if (tt + 2 < 64) stage(gB, buf, 32768, tt + 2, 0);
        BARRIER; LGKM0; SB0;
        __builtin_amdgcn_s_setprio(1);
        mm16(a4, b4, 1);
        __builtin_amdgcn_s_setprio(0);
        BARRIER;

        // phase 2: kk=1, mh=0; stage A_k0(t+2)
        SB0;
        ldA(a4, buf, 1, 0); ldB(b4, buf, 1);
        SB0;
        if (tt + 2 < 64) stage(gA, buf, 0, tt + 2, 0);
        BARRIER; LGKM0; SB0;
        __builtin_amdgcn_s_setprio(1);
        mm16(a4, b4, 0);
        __builtin_amdgcn_s_setprio(0);
        BARRIER;

        // phase 3: kk=1, mh=1; stage B_k1(t+2); counted vmcnt ONCE per tile
        SB0;
        ldA(a4, buf, 1, 1);
        SB0;
        if (tt + 2 < 64) stage(gB, buf, 49152, tt + 2, 1);
        BARRIER; LGKM0; SB0;
        __builtin_amdgcn_s_setprio(1);
        mm16(a4, b4, 1);
        __builtin_amdgcn_s_setprio(0);
        if (tt < 62) { asm volatile("s_waitcnt vmcnt(6)" ::: "memory"); }
        else         { asm volatile("s_waitcnt vmcnt(0)" ::: "memory"); }
        BARRIER;
    }

    // ---- epilogue stage 1: G = bf16(x - d*Z) into swizzled Gs overlay ----
    // lane owns rows wm*128+am*16+rowq+r, cols wn*64+nt*16+col -> bs=bx*4+wn
    const int bx4 = bx * 4;
    #pragma unroll
    for (int am = 0; am < 8; ++am) {
        const int irel = wm * 128 + am * 16 + rowq;
        float dv[4];
        #pragma unroll
        for (int r = 0; r < 4; ++r) dv[r] = dvec[i0 + irel + r];
        #pragma unroll
        for (int nt = 0; nt < 4; ++nt) {
            const int c = nt * 16 + col;
            const size_t xbase = ((size_t)(bx4 + wn) * N_NODES + i0 + irel) * CDIM + c;
            #pragma unroll
            for (int r = 0; r < 4; ++r) {
                const int row = irel + r;
                float g = x[xbase + (size_t)r * CDIM] - dv[r] * acc[am][nt][r];
                *(__hip_bfloat16*)(smem + wn * 32768 + row * 128 +
                                   ((c * 2) ^ ((row & 7) << 4))) = __float2bfloat16(g);
            }
        }
    }
    __syncthreads();

    // ---- epilogue stage 2: out = sigmoid(G·W^T); wave -> (bs, i-half) ----
    const int bsr2 = w >> 1, ihalf = w & 1;
    const size_t obase = (size_t)(bx4 + bsr2) * N_NODES + i0 + ihalf * 128;
    #pragma unroll
    for (int hh = 0; hh < 2; ++hh) {
        floatx4 o[8][4];
        #pragma unroll
        for (int a = 0; a < 8; ++a)
            #pragma unroll
            for (int b = 0; b < 4; ++b)
                o[a][b] = (floatx4){0.f, 0.f, 0.f, 0.f};
        #pragma unroll
        for (int ks = 0; ks < 2; ++ks) {
            short8 gf[8], wf[4];
            const int kb = ks * 64 + kqb;
            #pragma unroll
            for (int mt = 0; mt < 8; ++mt) {
                const int grow = ihalf * 128 + mt * 16 + ar;
                gf[mt] = *(const short8*)(smem + bsr2 * 32768 + grow * 128 +
                                          (kb ^ ((grow & 7) << 4)));
            }
            #pragma unroll
            for (int nt = 0; nt < 4; ++nt) {
                const int hrow = hh * 64 + nt * 16 + ar;
                wf[nt] = *(const short8*)(Wbs + hrow * 72 + ks * 32 + kq);
            }
            #pragma unroll
            for (int mt = 0; mt < 8; ++mt)
                #pragma unroll
                for (int nt = 0; nt < 4; ++nt)
                    o[mt][nt] = __builtin_amdgcn_mfma_f32_16x16x32_bf16(
                        gf[mt], wf[nt], o[mt][nt], 0, 0, 0);
        }
        #pragma unroll
        for (int mt = 0; mt < 8; ++mt) {
            #pragma unroll
            for (int nt = 0; nt < 4; ++nt) {
                const int h = hh * 64 + nt * 16 + col;
                #pragma unroll
                for (int r = 0; r < 4; ++r) {
                    const size_t i = obase + mt * 16 + rowq + r;
                    out[i * HDIM + h] = 1.f / (1.f + __expf(-o[mt][nt][r]));
                }
            }
        }
    }
}

// -------- legacy fallback path (small workspace): gemm->G, then k_out --------
__global__ __launch_bounds__(256) void k_gemm(const __hip_bfloat16* __restrict__ Ab,
                                              const __hip_bfloat16* __restrict__ Xt,
                                              const float* __restrict__ x,
                                              const float* __restrict__ dvec,
                                              __hip_bfloat16* __restrict__ G) {
    __shared__ __hip_bfloat16 As[128 * 32];
    __shared__ __hip_bfloat16 Bs[128 * 32];
    const int t = threadIdx.x;
    const int w = t >> 6, l = t & 63;
    const int i0 = blockIdx.y * 128;
    const int j0 = blockIdx.x * 128;
    const int wm = w >> 1, wn = w & 1;
    const int ar = l & 15;
    const int kq = (l >> 4) * 8;
    const int srow = t >> 2;
    const int skcol = (t & 3) * 8;

    floatx4 acc[4][4];
    #pragma unroll
    for (int a = 0; a < 4; ++a)
        #pragma unroll
        for (int b = 0; b < 4; ++b)
            acc[a][b] = (floatx4){0.f, 0.f, 0.f, 0.f};

    const __hip_bfloat16* gA0 = Ab + (size_t)(i0 + srow) * N_NODES + skcol;
    const __hip_bfloat16* gB0 = Xt + (size_t)(j0 + srow) * N_NODES + skcol;

    for (int k0 = 0; k0 < N_NODES; k0 += 32) {
        __syncthreads();
        gload_lds16(gA0 + k0,                        As + w * 512);
        gload_lds16(gA0 + (size_t)64 * N_NODES + k0, As + 2048 + w * 512);
        gload_lds16(gB0 + k0,                        Bs + w * 512);
        gload_lds16(gB0 + (size_t)64 * N_NODES + k0, Bs + 2048 + w * 512);
        __syncthreads();
        short8 af[4], bfr[4];
        #pragma unroll
        for (int mt = 0; mt < 4; ++mt)
            af[mt] = *(const short8*)(As + (wm * 64 + mt * 16 + ar) * 32 + kq);
        #pragma unroll
        for (int nt = 0; nt < 4; ++nt)
            bfr[nt] = *(const short8*)(Bs + (wn * 64 + nt * 16 + ar) * 32 + kq);
        #pragma unroll
        for (int mt = 0; mt < 4; ++mt)
            #pragma unroll
            for (int nt = 0; nt < 4; ++nt)
                acc[mt][nt] = __builtin_amdgcn_mfma_f32_16x16x32_bf16(
                    af[mt], bfr[nt], acc[mt][nt], 0, 0, 0);
    }

    #pragma unroll
    for (int mt = 0; mt < 4; ++mt) {
        const int ibase = i0 + wm * 64 + mt * 16 + (l >> 4) * 4;
        #pragma unroll
        for (int nt = 0; nt < 4; ++nt) {
            const int j = j0 + wn * 64 + nt * 16 + (l & 15);
            const int bs = j >> 6, c = j & 63;
            #pragma unroll
            for (int r = 0; r < 4; ++r) {
                const int i = ibase + r;
                const size_t xi = ((size_t)bs * N_NODES + i) * CDIM + c;
                float g = x[xi] - dvec[i] * acc[mt][nt][r];
                G[xi] = __float2bfloat16(g);
            }
        }
    }
}

__global__ __launch_bounds__(256) void k_out(const __hip_bfloat16* __restrict__ G,
                                             const float* __restrict__ W,
                                             float* __restrict__ out) {
    __shared__ float Wt[64 * 132];
    __shared__ __hip_bfloat16 Gs[32 * 64];
    const int t = threadIdx.x;
    const int bs = blockIdx.y;
    const int i0 = blockIdx.x * 32;
    #pragma unroll
    for (int it = 0; it < 32; ++it) {
        int p = it * 256 + t;
        int h = p & 127, c = p >> 7;
        Wt[c * 132 + h] = W[h * 64 + c];
    }
    const short4* gp4 = (const short4*)(G + ((size_t)bs * N_NODES + i0) * CDIM);
    ((short4*)Gs)[t]       = gp4[t];
    ((short4*)Gs)[256 + t] = gp4[256 + t];
    __syncthreads();

    const int hg = t & 31;
    const int ig = t >> 5;
    float acc[4][4] = {};
    #pragma unroll
    for (int c = 0; c < 64; ++c) {
        float4 wv = *(const float4*)(Wt + c * 132 + hg * 4);
        #pragma unroll
        for (int ii = 0; ii < 4; ++ii) {
            float g = __bfloat162float(Gs[(ig * 4 + ii) * 64 + c]);
            acc[ii][0] += g * wv.x;
            acc[ii][1] += g * wv.y;
            acc[ii][2] += g * wv.z;
            acc[ii][3] += g * wv.w;
        }
    }
    #pragma unroll
    for (int ii = 0; ii < 4; ++ii) {
        const int i = i0 + ig * 4 + ii;
        float4 o;
        o.x = 1.f / (1.f + __expf(-acc[ii][0]));
        o.y = 1.f / (1.f + __expf(-acc[ii][1]));
        o.z = 1.f / (1.f + __expf(-acc[ii][2]));
        o.w = 1.f / (1.f + __expf(-acc[ii][3]));
        *(float4*)(out + ((size_t)bs * N_NODES + i) * HDIM + hg * 4) = o;
    }
}

extern "C" void kernel_launch(void* const* d_in, const int* in_sizes, int n_in,
                              void* d_out, int out_size, void* d_ws, size_t ws_size,
                              hipStream_t stream) {
    const float* x = (const float*)d_in[0];   // [48][4096][64]
    const float* A = (const float*)d_in[1];   // [4096][4096]
    const float* W = (const float*)d_in[2];   // [128][64]
    float* out  = (float*)d_out;              // out0: 25165824 floats
    float* outA = out + 25165824;             // A passthrough

    char* ws = (char*)d_ws;
    float* dvec = (float*)ws;
    const size_t offD = 16384;
    const size_t szAb = (size_t)16777216 * 2;     // 32 MB
    const size_t szXt = (size_t)3072 * 4096 * 2;  // 24 MB

    if (ws_size >= offD + szAb + szXt) {
        // fused path: Ab, Xt in workspace; no G intermediate
        __hip_bfloat16* Ab = (__hip_bfloat16*)(ws + offD);
        __hip_bfloat16* Xt = (__hip_bfloat16*)(ws + offD + szAb);
        k_prep    <<<4096, 256, 0, stream>>>(A, outA, Ab, dvec);
        k_buildXt <<<dim3(64, 48), 256, 0, stream>>>(x, dvec, Xt);
        k_gemm_out<<<192, 512, 0, stream>>>(Ab, Xt, x, dvec, W, out);
    } else {
        // legacy fallback: Ab in (dead) out0 region, G in ws
        __hip_bfloat16* Ab = (__hip_bfloat16*)out;
        __hip_bfloat16* Xt = (__hip_bfloat16*)(ws + offD);
        __hip_bfloat16* G  = (__hip_bfloat16*)(ws + offD + szXt);
        k_prep    <<<4096, 256, 0, stream>>>(A, outA, Ab, dvec);
        k_buildXt <<<dim3(64, 48), 256, 0, stream>>>(x, dvec, Xt);
        k_gemm    <<<dim3(24, 32), 256, 0, stream>>>(Ab, Xt, x, dvec, G);
        k_out     <<<dim3(128, 48), 256, 0, stream>>>(G, W, out);
    }
}

// Round 3
// 373.978 us; speedup vs baseline: 1.2019x; 1.0242x over previous
//
#include <hip/hip_runtime.h>
#include <hip/hip_bf16.h>
#include <stdint.h>

typedef __attribute__((ext_vector_type(8))) short short8;
typedef __attribute__((ext_vector_type(4))) float floatx4;

#define N_NODES 4096
#define CDIM 64
#define HDIM 128

#define AS1 __attribute__((address_space(1)))
#define AS3 __attribute__((address_space(3)))

__device__ __forceinline__ void gload_lds16(const void* g, void* l) {
    __builtin_amdgcn_global_load_lds((const AS1 void*)g, (AS3 void*)l, 16, 0, 0);
}

#define SB0 __builtin_amdgcn_sched_barrier(0)
#define BARRIER __builtin_amdgcn_s_barrier()
#define LGKM0 asm volatile("s_waitcnt lgkmcnt(0)" ::: "memory")

// -------- kernel 1: fused rowsum + A passthrough copy + bf16 convert --------
__global__ __launch_bounds__(256) void k_prep(const float* __restrict__ A,
                                              float* __restrict__ outA,
                                              __hip_bfloat16* __restrict__ Ab,
                                              float* __restrict__ dvec) {
    const int row = blockIdx.x;
    const int t = threadIdx.x;
    const float4* Ar = (const float4*)(A + (size_t)row * N_NODES);
    float4* Or = (float4*)(outA + (size_t)row * N_NODES);
    short4* Br = (short4*)(Ab + (size_t)row * N_NODES);
    float s = 0.f;
    #pragma unroll
    for (int j = 0; j < 4; ++j) {
        int q = t + j * 256;
        float4 v = Ar[q];
        Or[q] = v;
        union { __hip_bfloat16 h[4]; short4 s4; } u;
        u.h[0] = __float2bfloat16(v.x);
        u.h[1] = __float2bfloat16(v.y);
        u.h[2] = __float2bfloat16(v.z);
        u.h[3] = __float2bfloat16(v.w);
        Br[q] = u.s4;
        s += v.x + v.y + v.z + v.w;
    }
    #pragma unroll
    for (int off = 32; off > 0; off >>= 1) s += __shfl_down(s, off, 64);
    __shared__ float ps[4];
    if ((t & 63) == 0) ps[t >> 6] = s;
    __syncthreads();
    if (t == 0) {
        float tot = ps[0] + ps[1] + ps[2] + ps[3];
        dvec[row] = rsqrtf(tot + 1.0f);
    }
}

// ------ kernel 2: Xt[(bs*64+c)][k] = bf16(d[k] * x[bs,k,c])  (K-major) ------
__global__ __launch_bounds__(256) void k_buildXt(const float* __restrict__ x,
                                                 const float* __restrict__ dvec,
                                                 __hip_bfloat16* __restrict__ Xt) {
    __shared__ float tile[64 * 65];
    __shared__ float dloc[64];
    const int t = threadIdx.x;
    const int bs = blockIdx.y;
    const int k0 = blockIdx.x * 64;
    const float* xp = x + ((size_t)bs * N_NODES + k0) * CDIM;
    const float4* xp4 = (const float4*)xp;
    #pragma unroll
    for (int it = 0; it < 4; ++it) {
        int q = it * 256 + t;
        float4 v = xp4[q];
        int p = q * 4;
        int kk = p >> 6, c = p & 63;
        tile[kk * 65 + c + 0] = v.x;
        tile[kk * 65 + c + 1] = v.y;
        tile[kk * 65 + c + 2] = v.z;
        tile[kk * 65 + c + 3] = v.w;
    }
    if (t < 64) dloc[t] = dvec[k0 + t];
    __syncthreads();
    #pragma unroll
    for (int it = 0; it < 16; ++it) {
        int p = it * 256 + t;
        int c = p >> 6;
        int kk = p & 63;
        float v = tile[kk * 65 + c] * dloc[kk];
        Xt[(size_t)(bs * CDIM + c) * N_NODES + k0 + kk] = __float2bfloat16(v);
    }
}

// ====== kernel 3: 256x256 8-phase GEMM (T2+T3+T4+T5) + fused epilogue ======
// Z = Ab·Xt^T; G = x - d*Z (LDS, swizzled); out = sigmoid(G·W^T) via MFMA.
// LDS map: [0,131072): dbuf[2] x {A_k0,A_k1,B_k0,B_k1}[256][32] bf16 subtiles.
//   Subtile rows are 64 B, so address bit 6 == row bit 0. Swizzle therefore
//   XORs row bits 1-2 into granule bits 4-5:  byte ^= ((row>>1)&3)<<4.
//   Combined granule (bits 4-6) = ((row&1)<<2) | (chunk ^ ((row>>1)&3)) —
//   each 8-lane service group covers 8 DISTINCT 16B granules (all 32 banks).
//   (Previous (row&3)<<4 aliased lanes ar and ar+4 -> measured 4-way conflict.)
//   Applied via pre-swizzled global source (linear gload_lds dest, rule 21)
//   + identical XOR on the ds_read side.
// Epilogue overlays as Gs[4][256][64] (128B rows, byte ^= (row&7)<<4).
// [131072,149504): Wbs [128][72] bf16 (padded, no conflicts).
__global__ __launch_bounds__(512, 2) void k_gemm_out(const __hip_bfloat16* __restrict__ Ab,
                                                     const __hip_bfloat16* __restrict__ Xt,
                                                     const float* __restrict__ x,
                                                     const float* __restrict__ dvec,
                                                     const float* __restrict__ W,
                                                     float* __restrict__ out) {
    __shared__ __align__(16) char smem[149504];
    __hip_bfloat16* Wbs = (__hip_bfloat16*)(smem + 131072);

    const int t = threadIdx.x;
    const int w = t >> 6, l = t & 63;
    const int wm = w >> 2, wn = w & 3;          // 2 x 4 wave grid
    const int ar = l & 15;
    const int kq = (l >> 4) * 8;                // k elem offset within 32-half
    const int kqb = kq * 2;                     // bytes: 0,16,32,48
    const int col = l & 15;
    const int rowq = (l >> 4) * 4;
    const int xorR = ((ar >> 1) & 3) << 4;      // read swizzle: row bits 1-2 -> bits 4-5

    // XCD-bijective block swizzle (192 blocks, 192%8==0)
    const int flat = blockIdx.x;
    const int tid2 = (flat & 7) * 24 + (flat >> 3);
    const int bx = tid2 % 12;                   // N tiles (3072/256)
    const int by = tid2 / 12;                   // M tiles (4096/256)
    const int i0 = by * 256;
    const int j0 = bx * 256;

    // ---- stage W -> Wbs (padded [128][72]) ----
    {
        const float4* W4 = (const float4*)W;    // 2048 float4
        #pragma unroll
        for (int it = 0; it < 4; ++it) {
            int q4 = it * 512 + t;
            float4 v = W4[q4];
            int p = q4 * 4;                     // h*64 + c, c%4==0
            int h = p >> 6, c = p & 63;
            union { __hip_bfloat16 hh[4]; short4 s4; } u;
            u.hh[0] = __float2bfloat16(v.x);
            u.hh[1] = __float2bfloat16(v.y);
            u.hh[2] = __float2bfloat16(v.z);
            u.hh[3] = __float2bfloat16(v.w);
            *(short4*)(Wbs + h * 72 + c) = u.s4;
        }
    }
    SB0;

    // ---- per-lane pre-swizzled global source for staging ----
    // lane covers row rloc = w*16 + (l>>2), lds 16B-slot (l&3);
    // stored slot s of row r must hold global chunk s ^ ((r>>1)&3).
    // (r>>1)&3 for r = rloc (+128 for rd=1): both reduce to (l>>3)&3.
    const int rloc = w * 16 + (l >> 2);
    const int slot = (l & 3) ^ ((rloc >> 1) & 3);
    const __hip_bfloat16* gA = Ab + (size_t)(i0 + rloc) * N_NODES + slot * 8;
    const __hip_bfloat16* gB = Xt + (size_t)(j0 + rloc) * N_NODES + slot * 8;

    // stage one 16KB [256][32] subtile of K-tile `tile`, k-half kk
    auto stage = [&](const __hip_bfloat16* gbase, int buf, int subByte, int tile, int kk) {
        const __hip_bfloat16* g = gbase + tile * 64 + kk * 32;
        char* d = smem + buf * 65536 + subByte + w * 1024;
        gload_lds16(g, d);                           // rows rloc (rd=0)
        gload_lds16(g + (size_t)128 * N_NODES, d + 8192);  // rows rloc+128 (rd=1)
    };

    floatx4 acc[8][4];
    #pragma unroll
    for (int a = 0; a < 8; ++a)
        #pragma unroll
        for (int b = 0; b < 4; ++b)
            acc[a][b] = (floatx4){0.f, 0.f, 0.f, 0.f};

    // fragment readers (swizzled)
    auto ldA = [&](short8* dst, int buf, int kk, int mh) {
        const char* base = smem + buf * 65536 + kk * 16384;
        const int off = (wm * 128 + mh * 64 + ar) * 64 + (kqb ^ xorR);
        #pragma unroll
        for (int mt = 0; mt < 4; ++mt)
            dst[mt] = *(const short8*)(base + off + mt * 1024);
    };
    auto ldB = [&](short8* dst, int buf, int kk) {
        const char* base = smem + buf * 65536 + 32768 + kk * 16384;
        const int off = (wn * 64 + ar) * 64 + (kqb ^ xorR);
        #pragma unroll
        for (int nt = 0; nt < 4; ++nt)
            dst[nt] = *(const short8*)(base + off + nt * 1024);
    };
    auto mm16 = [&](const short8* a, const short8* b, int mh) {
        #pragma unroll
        for (int mt = 0; mt < 4; ++mt)
            #pragma unroll
            for (int nt = 0; nt < 4; ++nt)
                acc[mh * 4 + mt][nt] = __builtin_amdgcn_mfma_f32_16x16x32_bf16(
                    a[mt], b[nt], acc[mh * 4 + mt][nt], 0, 0, 0);
    };

    // ---- prologue: tile0 (4 subtiles) + tile1 (3 subtiles); wait oldest 8 ----
    stage(gA, 0, 0,     0, 0);   // A_k0(0)
    stage(gB, 0, 32768, 0, 0);   // B_k0(0)
    stage(gA, 0, 16384, 0, 1);   // A_k1(0)
    stage(gB, 0, 49152, 0, 1);   // B_k1(0)
    stage(gB, 1, 32768, 1, 0);   // B_k0(1)
    stage(gA, 1, 0,     1, 0);   // A_k0(1)
    stage(gB, 1, 49152, 1, 1);   // B_k1(1)
    asm volatile("s_waitcnt vmcnt(6)" ::: "memory");
    BARRIER;

    // ---- main loop: 64 K-tiles, 4 phases each ----
    #pragma unroll 2
    for (int tt = 0; tt < 64; ++tt) {
        const int buf = tt & 1;
        short8 a4[4], b4[4];

        // phase 0: kk=0, mh=0 (reads A_k0 lower + all B_k0); stage A_k1(t+1)
        SB0;
        ldA(a4, buf, 0, 0); ldB(b4, buf, 0);
        SB0;
        if (tt + 1 < 64) stage(gA, buf ^ 1, 16384, tt + 1, 1);
        BARRIER; LGKM0; SB0;
        __builtin_amdgcn_s_setprio(1);
        mm16(a4, b4, 0);
        __builtin_amdgcn_s_setprio(0);
        BARRIER;

        // phase 1: kk=0, mh=1 (A_k0 upper; B regs reused); stage B_k0(t+2)
        SB0;
        ldA(a4, buf, 0, 1);
        SB0;
        if (tt + 2 < 64) stage(gB, buf, 32768, tt + 2, 0);
        BARRIER; LGKM0; SB0;
        __builtin_amdgcn_s_setprio(1);
        mm16(a4, b4, 1);
        __builtin_amdgcn_s_setprio(0);
        BARRIER;

        // phase 2: kk=1, mh=0; stage A_k0(t+2)
        SB0;
        ldA(a4, buf, 1, 0); ldB(b4, buf, 1);
        SB0;
        if (tt + 2 < 64) stage(gA, buf, 0, tt + 2, 0);
        BARRIER; LGKM0; SB0;
        __builtin_amdgcn_s_setprio(1);
        mm16(a4, b4, 0);
        __builtin_amdgcn_s_setprio(0);
        BARRIER;

        // phase 3: kk=1, mh=1; stage B_k1(t+2); counted vmcnt ONCE per tile
        SB0;
        ldA(a4, buf, 1, 1);
        SB0;
        if (tt + 2 < 64) stage(gB, buf, 49152, tt + 2, 1);
        BARRIER; LGKM0; SB0;
        __builtin_amdgcn_s_setprio(1);
        mm16(a4, b4, 1);
        __builtin_amdgcn_s_setprio(0);
        if (tt < 62) { asm volatile("s_waitcnt vmcnt(6)" ::: "memory"); }
        else         { asm volatile("s_waitcnt vmcnt(0)" ::: "memory"); }
        BARRIER;
    }

    // ---- epilogue stage 1: G = bf16(x - d*Z) into swizzled Gs overlay ----
    // lane owns rows wm*128+am*16+rowq+r, cols wn*64+nt*16+col -> bs=bx*4+wn
    const int bx4 = bx * 4;
    #pragma unroll
    for (int am = 0; am < 8; ++am) {
        const int irel = wm * 128 + am * 16 + rowq;
        float dv[4];
        #pragma unroll
        for (int r = 0; r < 4; ++r) dv[r] = dvec[i0 + irel + r];
        #pragma unroll
        for (int nt = 0; nt < 4; ++nt) {
            const int c = nt * 16 + col;
            const size_t xbase = ((size_t)(bx4 + wn) * N_NODES + i0 + irel) * CDIM + c;
            #pragma unroll
            for (int r = 0; r < 4; ++r) {
                const int row = irel + r;
                float g = x[xbase + (size_t)r * CDIM] - dv[r] * acc[am][nt][r];
                *(__hip_bfloat16*)(smem + wn * 32768 + row * 128 +
                                   ((c * 2) ^ ((row & 7) << 4))) = __float2bfloat16(g);
            }
        }
    }
    __syncthreads();

    // ---- epilogue stage 2: out = sigmoid(G·W^T); wave -> (bs, i-half) ----
    const int bsr2 = w >> 1, ihalf = w & 1;
    const size_t obase = (size_t)(bx4 + bsr2) * N_NODES + i0 + ihalf * 128;
    #pragma unroll
    for (int hh = 0; hh < 2; ++hh) {
        floatx4 o[8][4];
        #pragma unroll
        for (int a = 0; a < 8; ++a)
            #pragma unroll
            for (int b = 0; b < 4; ++b)
                o[a][b] = (floatx4){0.f, 0.f, 0.f, 0.f};
        #pragma unroll
        for (int ks = 0; ks < 2; ++ks) {
            short8 gf[8], wf[4];
            const int kb = ks * 64 + kqb;
            #pragma unroll
            for (int mt = 0; mt < 8; ++mt) {
                const int grow = ihalf * 128 + mt * 16 + ar;
                gf[mt] = *(const short8*)(smem + bsr2 * 32768 + grow * 128 +
                                          (kb ^ ((grow & 7) << 4)));
            }
            #pragma unroll
            for (int nt = 0; nt < 4; ++nt) {
                const int hrow = hh * 64 + nt * 16 + ar;
                wf[nt] = *(const short8*)(Wbs + hrow * 72 + ks * 32 + kq);
            }
            #pragma unroll
            for (int mt = 0; mt < 8; ++mt)
                #pragma unroll
                for (int nt = 0; nt < 4; ++nt)
                    o[mt][nt] = __builtin_amdgcn_mfma_f32_16x16x32_bf16(
                        gf[mt], wf[nt], o[mt][nt], 0, 0, 0);
        }
        #pragma unroll
        for (int mt = 0; mt < 8; ++mt) {
            #pragma unroll
            for (int nt = 0; nt < 4; ++nt) {
                const int h = hh * 64 + nt * 16 + col;
                #pragma unroll
                for (int r = 0; r < 4; ++r) {
                    const size_t i = obase + mt * 16 + rowq + r;
                    out[i * HDIM + h] = 1.f / (1.f + __expf(-o[mt][nt][r]));
                }
            }
        }
    }
}

// -------- legacy fallback path (small workspace): gemm->G, then k_out --------
__global__ __launch_bounds__(256) void k_gemm(const __hip_bfloat16* __restrict__ Ab,
                                              const __hip_bfloat16* __restrict__ Xt,
                                              const float* __restrict__ x,
                                              const float* __restrict__ dvec,
                                              __hip_bfloat16* __restrict__ G) {
    __shared__ __hip_bfloat16 As[128 * 32];
    __shared__ __hip_bfloat16 Bs[128 * 32];
    const int t = threadIdx.x;
    const int w = t >> 6, l = t & 63;
    const int i0 = blockIdx.y * 128;
    const int j0 = blockIdx.x * 128;
    const int wm = w >> 1, wn = w & 1;
    const int ar = l & 15;
    const int kq = (l >> 4) * 8;
    const int srow = t >> 2;
    const int skcol = (t & 3) * 8;

    floatx4 acc[4][4];
    #pragma unroll
    for (int a = 0; a < 4; ++a)
        #pragma unroll
        for (int b = 0; b < 4; ++b)
            acc[a][b] = (floatx4){0.f, 0.f, 0.f, 0.f};

    const __hip_bfloat16* gA0 = Ab + (size_t)(i0 + srow) * N_NODES + skcol;
    const __hip_bfloat16* gB0 = Xt + (size_t)(j0 + srow) * N_NODES + skcol;

    for (int k0 = 0; k0 < N_NODES; k0 += 32) {
        __syncthreads();
        gload_lds16(gA0 + k0,                        As + w * 512);
        gload_lds16(gA0 + (size_t)64 * N_NODES + k0, As + 2048 + w * 512);
        gload_lds16(gB0 + k0,                        Bs + w * 512);
        gload_lds16(gB0 + (size_t)64 * N_NODES + k0, Bs + 2048 + w * 512);
        __syncthreads();
        short8 af[4], bfr[4];
        #pragma unroll
        for (int mt = 0; mt < 4; ++mt)
            af[mt] = *(const short8*)(As + (wm * 64 + mt * 16 + ar) * 32 + kq);
        #pragma unroll
        for (int nt = 0; nt < 4; ++nt)
            bfr[nt] = *(const short8*)(Bs + (wn * 64 + nt * 16 + ar) * 32 + kq);
        #pragma unroll
        for (int mt = 0; mt < 4; ++mt)
            #pragma unroll
            for (int nt = 0; nt < 4; ++nt)
                acc[mt][nt] = __builtin_amdgcn_mfma_f32_16x16x32_bf16(
                    af[mt], bfr[nt], acc[mt][nt], 0, 0, 0);
    }

    #pragma unroll
    for (int mt = 0; mt < 4; ++mt) {
        const int ibase = i0 + wm * 64 + mt * 16 + (l >> 4) * 4;
        #pragma unroll
        for (int nt = 0; nt < 4; ++nt) {
            const int j = j0 + wn * 64 + nt * 16 + (l & 15);
            const int bs = j >> 6, c = j & 63;
            #pragma unroll
            for (int r = 0; r < 4; ++r) {
                const int i = ibase + r;
                const size_t xi = ((size_t)bs * N_NODES + i) * CDIM + c;
                float g = x[xi] - dvec[i] * acc[mt][nt][r];
                G[xi] = __float2bfloat16(g);
            }
        }
    }
}

__global__ __launch_bounds__(256) void k_out(const __hip_bfloat16* __restrict__ G,
                                             const float* __restrict__ W,
                                             float* __restrict__ out) {
    __shared__ float Wt[64 * 132];
    __shared__ __hip_bfloat16 Gs[32 * 64];
    const int t = threadIdx.x;
    const int bs = blockIdx.y;
    const int i0 = blockIdx.x * 32;
    #pragma unroll
    for (int it = 0; it < 32; ++it) {
        int p = it * 256 + t;
        int h = p & 127, c = p >> 7;
        Wt[c * 132 + h] = W[h * 64 + c];
    }
    const short4* gp4 = (const short4*)(G + ((size_t)bs * N_NODES + i0) * CDIM);
    ((short4*)Gs)[t]       = gp4[t];
    ((short4*)Gs)[256 + t] = gp4[256 + t];
    __syncthreads();

    const int hg = t & 31;
    const int ig = t >> 5;
    float acc[4][4] = {};
    #pragma unroll
    for (int c = 0; c < 64; ++c) {
        float4 wv = *(const float4*)(Wt + c * 132 + hg * 4);
        #pragma unroll
        for (int ii = 0; ii < 4; ++ii) {
            float g = __bfloat162float(Gs[(ig * 4 + ii) * 64 + c]);
            acc[ii][0] += g * wv.x;
            acc[ii][1] += g * wv.y;
            acc[ii][2] += g * wv.z;
            acc[ii][3] += g * wv.w;
        }
    }
    #pragma unroll
    for (int ii = 0; ii < 4; ++ii) {
        const int i = i0 + ig * 4 + ii;
        float4 o;
        o.x = 1.f / (1.f + __expf(-acc[ii][0]));
        o.y = 1.f / (1.f + __expf(-acc[ii][1]));
        o.z = 1.f / (1.f + __expf(-acc[ii][2]));
        o.w = 1.f / (1.f + __expf(-acc[ii][3]));
        *(float4*)(out + ((size_t)bs * N_NODES + i) * HDIM + hg * 4) = o;
    }
}

extern "C" void kernel_launch(void* const* d_in, const int* in_sizes, int n_in,
                              void* d_out, int out_size, void* d_ws, size_t ws_size,
                              hipStream_t stream) {
    const float* x = (const float*)d_in[0];   // [48][4096][64]
    const float* A = (const float*)d_in[1];   // [4096][4096]
    const float* W = (const float*)d_in[2];   // [128][64]
    float* out  = (float*)d_out;              // out0: 25165824 floats
    float* outA = out + 25165824;             // A passthrough

    char* ws = (char*)d_ws;
    float* dvec = (float*)ws;
    const size_t offD = 16384;
    const size_t szAb = (size_t)16777216 * 2;     // 32 MB
    const size_t szXt = (size_t)3072 * 4096 * 2;  // 24 MB

    if (ws_size >= offD + szAb + szXt) {
        // fused path: Ab, Xt in workspace; no G intermediate
        __hip_bfloat16* Ab = (__hip_bfloat16*)(ws + offD);
        __hip_bfloat16* Xt = (__hip_bfloat16*)(ws + offD + szAb);
        k_prep    <<<4096, 256, 0, stream>>>(A, outA, Ab, dvec);
        k_buildXt <<<dim3(64, 48), 256, 0, stream>>>(x, dvec, Xt);
        k_gemm_out<<<192, 512, 0, stream>>>(Ab, Xt, x, dvec, W, out);
    } else {
        // legacy fallback: Ab in (dead) out0 region, G in ws
        __hip_bfloat16* Ab = (__hip_bfloat16*)out;
        __hip_bfloat16* Xt = (__hip_bfloat16*)(ws + offD);
        __hip_bfloat16* G  = (__hip_bfloat16*)(ws + offD + szXt);
        k_prep    <<<4096, 256, 0, stream>>>(A, outA, Ab, dvec);
        k_buildXt <<<dim3(64, 48), 256, 0, stream>>>(x, dvec, Xt);
        k_gemm    <<<dim3(24, 32), 256, 0, stream>>>(Ab, Xt, x, dvec, G);
        k_out     <<<dim3(128, 48), 256, 0, stream>>>(G, W, out);
    }
}

// Round 4
// 355.532 us; speedup vs baseline: 1.2643x; 1.0519x over previous
//
#include <hip/hip_runtime.h>
#include <hip/hip_bf16.h>
#include <stdint.h>

typedef __attribute__((ext_vector_type(8))) short short8;
typedef __attribute__((ext_vector_type(4))) float floatx4;

#define N_NODES 4096
#define CDIM 64
#define HDIM 128

#define AS1 __attribute__((address_space(1)))
#define AS3 __attribute__((address_space(3)))

__device__ __forceinline__ void gload_lds16(const void* g, void* l) {
    __builtin_amdgcn_global_load_lds((const AS1 void*)g, (AS3 void*)l, 16, 0, 0);
}

#define SB0 __builtin_amdgcn_sched_barrier(0)
#define BARRIER __builtin_amdgcn_s_barrier()
#define LGKM0 asm volatile("s_waitcnt lgkmcnt(0)" ::: "memory")

// -------- kernel 1: fused rowsum + A passthrough copy + bf16 convert --------
__global__ __launch_bounds__(256) void k_prep(const float* __restrict__ A,
                                              float* __restrict__ outA,
                                              __hip_bfloat16* __restrict__ Ab,
                                              float* __restrict__ dvec) {
    const int row = blockIdx.x;
    const int t = threadIdx.x;
    const float4* Ar = (const float4*)(A + (size_t)row * N_NODES);
    float4* Or = (float4*)(outA + (size_t)row * N_NODES);
    short4* Br = (short4*)(Ab + (size_t)row * N_NODES);
    float s = 0.f;
    #pragma unroll
    for (int j = 0; j < 4; ++j) {
        int q = t + j * 256;
        float4 v = Ar[q];
        Or[q] = v;
        union { __hip_bfloat16 h[4]; short4 s4; } u;
        u.h[0] = __float2bfloat16(v.x);
        u.h[1] = __float2bfloat16(v.y);
        u.h[2] = __float2bfloat16(v.z);
        u.h[3] = __float2bfloat16(v.w);
        Br[q] = u.s4;
        s += v.x + v.y + v.z + v.w;
    }
    #pragma unroll
    for (int off = 32; off > 0; off >>= 1) s += __shfl_down(s, off, 64);
    __shared__ float ps[4];
    if ((t & 63) == 0) ps[t >> 6] = s;
    __syncthreads();
    if (t == 0) {
        float tot = ps[0] + ps[1] + ps[2] + ps[3];
        dvec[row] = rsqrtf(tot + 1.0f);
    }
}

// ------ kernel 2: Xt[(bs*64+c)][k] = bf16(d[k] * x[bs,k,c])  (K-major) ------
__global__ __launch_bounds__(256) void k_buildXt(const float* __restrict__ x,
                                                 const float* __restrict__ dvec,
                                                 __hip_bfloat16* __restrict__ Xt) {
    __shared__ float tile[64 * 65];
    __shared__ float dloc[64];
    const int t = threadIdx.x;
    const int bs = blockIdx.y;
    const int k0 = blockIdx.x * 64;
    const float* xp = x + ((size_t)bs * N_NODES + k0) * CDIM;
    const float4* xp4 = (const float4*)xp;
    #pragma unroll
    for (int it = 0; it < 4; ++it) {
        int q = it * 256 + t;
        float4 v = xp4[q];
        int p = q * 4;
        int kk = p >> 6, c = p & 63;
        tile[kk * 65 + c + 0] = v.x;
        tile[kk * 65 + c + 1] = v.y;
        tile[kk * 65 + c + 2] = v.z;
        tile[kk * 65 + c + 3] = v.w;
    }
    if (t < 64) dloc[t] = dvec[k0 + t];
    __syncthreads();
    #pragma unroll
    for (int it = 0; it < 16; ++it) {
        int p = it * 256 + t;
        int c = p >> 6;
        int kk = p & 63;
        float v = tile[kk * 65 + c] * dloc[kk];
        Xt[(size_t)(bs * CDIM + c) * N_NODES + k0 + kk] = __float2bfloat16(v);
    }
}

// ====== kernel 3: 256x192-tile 8-phase GEMM (grid 256 = 1 block/CU) ======
// Z = Ab·Xt^T; G = x - d*Z (LDS, swizzled); out = sigmoid(G·W^T) via MFMA.
// Grid 16x16 = 256 blocks -> every CU busy (was 192 blocks = 64 CUs idle).
// LDS map:
//   [0,65536):        A dbuf[2] x {k0,k1}[256][32] bf16 (16KB each).
//     64B rows: bit6==row bit0 -> swizzle byte ^= ((row>>1)&3)<<4 (verified r3).
//   [65536,114688):   B dbuf[2] x [192][64] bf16 (24KB each).
//     128B rows: full swizzle byte ^= ((row&7)<<4) (same pattern as Gs reads,
//     verified near-zero conflicts r3). Staged as 24 x 1KB segs, 3/wave.
//   epilogue overlay: Gs[3][256][64] (96KB) over the dbuf region.
//   [114688,133120):  Wbs [128][72] bf16 (padded).
// Staging liveness (stage region only >=1 barrier-pair after last read):
//   ph0: stage A_k1(t+1)  (A_k1(buf^1) last read t-1 ph3)
//   ph2: stage A_k0(t+2)  (A_k0(buf) last read t ph1)
//   ph3: stage B(t+2)     (B(buf) last read t ph2)
// 7 loads/wave/tile, uniform; steady-state tail wait vmcnt(5).
__global__ __launch_bounds__(512, 2) void k_gemm_out(const __hip_bfloat16* __restrict__ Ab,
                                                     const __hip_bfloat16* __restrict__ Xt,
                                                     const float* __restrict__ x,
                                                     const float* __restrict__ dvec,
                                                     const float* __restrict__ W,
                                                     float* __restrict__ out) {
    __shared__ __align__(16) char smem[133120];
    __hip_bfloat16* Wbs = (__hip_bfloat16*)(smem + 114688);

    const int t = threadIdx.x;
    const int w = t >> 6, l = t & 63;
    const int wm = w >> 2, wn = w & 3;          // 2 x 4 wave grid; wave tile 128x48
    const int ar = l & 15;
    const int kq = (l >> 4) * 8;                // k elem offset within 32-half
    const int kqb = kq * 2;                     // bytes: 0,16,32,48
    const int col = l & 15;
    const int rowq = (l >> 4) * 4;
    const int xorA = ((ar >> 1) & 3) << 4;      // A read swizzle (row bits 1-2)
    const int xorB = (ar & 7) << 4;             // B read swizzle (row bits 0-2)

    // XCD-bijective block swizzle (256 blocks, 256%8==0)
    const int flat = blockIdx.x;
    const int tid2 = (flat & 7) * 32 + (flat >> 3);
    const int bx = tid2 & 15;                   // N tiles (3072/192 = 16)
    const int by = tid2 >> 4;                   // M tiles (4096/256 = 16)
    const int i0 = by * 256;
    const int j0 = bx * 192;

    // ---- stage W -> Wbs (padded [128][72]) ----
    {
        const float4* W4 = (const float4*)W;    // 2048 float4
        #pragma unroll
        for (int it = 0; it < 4; ++it) {
            int q4 = it * 512 + t;
            float4 v = W4[q4];
            int p = q4 * 4;                     // h*64 + c, c%4==0
            int h = p >> 6, c = p & 63;
            union { __hip_bfloat16 hh[4]; short4 s4; } u;
            u.hh[0] = __float2bfloat16(v.x);
            u.hh[1] = __float2bfloat16(v.y);
            u.hh[2] = __float2bfloat16(v.z);
            u.hh[3] = __float2bfloat16(v.w);
            *(short4*)(Wbs + h * 72 + c) = u.s4;
        }
    }
    SB0;

    // ---- A staging: per-lane pre-swizzled source (unchanged from r3) ----
    // lane covers row rloc = w*16 + (l>>2), 16B-slot (l&3);
    // stored slot s of row r holds global chunk s ^ ((r>>1)&3); +128 rows same.
    const int rloc = w * 16 + (l >> 2);
    const int slotA = (l & 3) ^ ((rloc >> 1) & 3);
    const __hip_bfloat16* gA = Ab + (size_t)(i0 + rloc) * N_NODES + slotA * 8;

    // A subtile [256][32]: 2 gloads/wave
    auto stageA = [&](int buf, int kk, int tile) {
        const __hip_bfloat16* g = gA + tile * 64 + kk * 32;
        char* d = smem + buf * 32768 + kk * 16384 + w * 1024;
        gload_lds16(g, d);                                  // rows rloc
        gload_lds16(g + (size_t)128 * N_NODES, d + 8192);   // rows rloc+128
    };

    // ---- B staging: [192][64] tile, 24 segments of 1KB, 3/wave ----
    // segment s covers rows 8s..8s+7; lane l -> row 8s+(l>>3), slot (l&7);
    // stored slot q of row r holds global chunk q ^ (r&7); r&7 == l>>3.
    const int brow_l = l >> 3;
    const int bchunk = (l & 7) ^ brow_l;
    const __hip_bfloat16* gB = Xt + (size_t)(j0 + brow_l) * N_NODES + bchunk * 8;

    auto stageB = [&](int buf, int tile) {
        #pragma unroll
        for (int i = 0; i < 3; ++i) {
            const int seg = 3 * w + i;
            gload_lds16(gB + (size_t)(8 * seg) * N_NODES + tile * 64,
                        smem + 65536 + buf * 24576 + seg * 1024);
        }
    };

    floatx4 acc[8][3];
    #pragma unroll
    for (int a = 0; a < 8; ++a)
        #pragma unroll
        for (int b = 0; b < 3; ++b)
            acc[a][b] = (floatx4){0.f, 0.f, 0.f, 0.f};

    // fragment readers (swizzled)
    auto ldA = [&](short8* dst, int buf, int kk, int mh) {
        const char* base = smem + buf * 32768 + kk * 16384;
        const int off = (wm * 128 + mh * 64 + ar) * 64 + (kqb ^ xorA);
        #pragma unroll
        for (int mt = 0; mt < 4; ++mt)
            dst[mt] = *(const short8*)(base + off + mt * 1024);
    };
    auto ldB = [&](short8* dst, int buf, int kk) {
        const char* base = smem + 65536 + buf * 24576;
        const int off = (wn * 48 + ar) * 128 + ((kk * 64 + kqb) ^ xorB);
        #pragma unroll
        for (int nt = 0; nt < 3; ++nt)
            dst[nt] = *(const short8*)(base + off + nt * 2048);
    };
    auto mm12 = [&](const short8* a, const short8* b, int mh) {
        #pragma unroll
        for (int mt = 0; mt < 4; ++mt)
            #pragma unroll
            for (int nt = 0; nt < 3; ++nt)
                acc[mh * 4 + mt][nt] = __builtin_amdgcn_mfma_f32_16x16x32_bf16(
                    a[mt], b[nt], acc[mh * 4 + mt][nt], 0, 0, 0);
    };

    // ---- prologue: tile0 full (7) + A0(1):2 + B(1):3; wait 7 oldest ----
    stageA(0, 0, 0);
    stageA(0, 1, 0);
    stageB(0, 0);
    stageA(1, 0, 1);
    stageB(1, 1);
    asm volatile("s_waitcnt vmcnt(5)" ::: "memory");
    BARRIER;

    // ---- main loop: 64 K-tiles, 4 phases each ----
    #pragma unroll 2
    for (int tt = 0; tt < 64; ++tt) {
        const int buf = tt & 1;
        short8 a4[4], b3[3];

        // phase 0: kk=0, mh=0; stage A_k1(t+1) -> buf^1
        SB0;
        ldA(a4, buf, 0, 0); ldB(b3, buf, 0);
        SB0;
        if (tt + 1 < 64) stageA(buf ^ 1, 1, tt + 1);
        BARRIER; LGKM0; SB0;
        __builtin_amdgcn_s_setprio(1);
        mm12(a4, b3, 0);
        __builtin_amdgcn_s_setprio(0);
        BARRIER;

        // phase 1: kk=0, mh=1 (B regs reused)
        SB0;
        ldA(a4, buf, 0, 1);
        SB0;
        BARRIER; LGKM0; SB0;
        __builtin_amdgcn_s_setprio(1);
        mm12(a4, b3, 1);
        __builtin_amdgcn_s_setprio(0);
        BARRIER;

        // phase 2: kk=1, mh=0; stage A_k0(t+2) -> buf
        SB0;
        ldA(a4, buf, 1, 0); ldB(b3, buf, 1);
        SB0;
        if (tt + 2 < 64) stageA(buf, 0, tt + 2);
        BARRIER; LGKM0; SB0;
        __builtin_amdgcn_s_setprio(1);
        mm12(a4, b3, 0);
        __builtin_amdgcn_s_setprio(0);
        BARRIER;

        // phase 3: kk=1, mh=1; stage B(t+2) -> buf; counted vmcnt once/tile
        SB0;
        ldA(a4, buf, 1, 1);
        SB0;
        if (tt + 2 < 64) stageB(buf, tt + 2);
        BARRIER; LGKM0; SB0;
        __builtin_amdgcn_s_setprio(1);
        mm12(a4, b3, 1);
        __builtin_amdgcn_s_setprio(0);
        if (tt < 62) { asm volatile("s_waitcnt vmcnt(5)" ::: "memory"); }
        else         { asm volatile("s_waitcnt vmcnt(0)" ::: "memory"); }
        BARRIER;
    }

    // ---- epilogue stage 1: G = bf16(x - d*Z) into swizzled Gs overlay ----
    // cols jrel = wn*48 + nt*16 + col (0..191) -> bsr = jrel>>6 (3 bs/block)
    const int bx3 = bx * 3;
    #pragma unroll
    for (int am = 0; am < 8; ++am) {
        const int irel = wm * 128 + am * 16 + rowq;
        float dv[4];
        #pragma unroll
        for (int r = 0; r < 4; ++r) dv[r] = dvec[i0 + irel + r];
        #pragma unroll
        for (int nt = 0; nt < 3; ++nt) {
            const int jrel = wn * 48 + nt * 16 + col;
            const int bsr = jrel >> 6, c = jrel & 63;
            const size_t xbase = ((size_t)(bx3 + bsr) * N_NODES + i0 + irel) * CDIM + c;
            #pragma unroll
            for (int r = 0; r < 4; ++r) {
                const int row = irel + r;
                float g = x[xbase + (size_t)r * CDIM] - dv[r] * acc[am][nt][r];
                *(__hip_bfloat16*)(smem + bsr * 32768 + row * 128 +
                                   ((c * 2) ^ ((row & 7) << 4))) = __float2bfloat16(g);
            }
        }
    }
    __syncthreads();

    // ---- epilogue stage 2: out = sigmoid(G·W^T); waves 0-5 -> (bs, i-half) ----
    if (w < 6) {
        const int bsr2 = w >> 1, ihalf = w & 1;
        const size_t obase = (size_t)(bx3 + bsr2) * N_NODES + i0 + ihalf * 128;
        #pragma unroll
        for (int hh = 0; hh < 2; ++hh) {
            floatx4 o[8][4];
            #pragma unroll
            for (int a = 0; a < 8; ++a)
                #pragma unroll
                for (int b = 0; b < 4; ++b)
                    o[a][b] = (floatx4){0.f, 0.f, 0.f, 0.f};
            #pragma unroll
            for (int ks = 0; ks < 2; ++ks) {
                short8 gf[8], wf[4];
                const int kb = ks * 64 + kqb;
                #pragma unroll
                for (int mt = 0; mt < 8; ++mt) {
                    const int grow = ihalf * 128 + mt * 16 + ar;
                    gf[mt] = *(const short8*)(smem + bsr2 * 32768 + grow * 128 +
                                              (kb ^ ((grow & 7) << 4)));
                }
                #pragma unroll
                for (int nt = 0; nt < 4; ++nt) {
                    const int hrow = hh * 64 + nt * 16 + ar;
                    wf[nt] = *(const short8*)(Wbs + hrow * 72 + ks * 32 + kq);
                }
                #pragma unroll
                for (int mt = 0; mt < 8; ++mt)
                    #pragma unroll
                    for (int nt = 0; nt < 4; ++nt)
                        o[mt][nt] = __builtin_amdgcn_mfma_f32_16x16x32_bf16(
                            gf[mt], wf[nt], o[mt][nt], 0, 0, 0);
            }
            #pragma unroll
            for (int mt = 0; mt < 8; ++mt) {
                #pragma unroll
                for (int nt = 0; nt < 4; ++nt) {
                    const int h = hh * 64 + nt * 16 + col;
                    #pragma unroll
                    for (int r = 0; r < 4; ++r) {
                        const size_t i = obase + mt * 16 + rowq + r;
                        out[i * HDIM + h] = 1.f / (1.f + __expf(-o[mt][nt][r]));
                    }
                }
            }
        }
    }
}

// -------- legacy fallback path (small workspace): gemm->G, then k_out --------
__global__ __launch_bounds__(256) void k_gemm(const __hip_bfloat16* __restrict__ Ab,
                                              const __hip_bfloat16* __restrict__ Xt,
                                              const float* __restrict__ x,
                                              const float* __restrict__ dvec,
                                              __hip_bfloat16* __restrict__ G) {
    __shared__ __hip_bfloat16 As[128 * 32];
    __shared__ __hip_bfloat16 Bs[128 * 32];
    const int t = threadIdx.x;
    const int w = t >> 6, l = t & 63;
    const int i0 = blockIdx.y * 128;
    const int j0 = blockIdx.x * 128;
    const int wm = w >> 1, wn = w & 1;
    const int ar = l & 15;
    const int kq = (l >> 4) * 8;
    const int srow = t >> 2;
    const int skcol = (t & 3) * 8;

    floatx4 acc[4][4];
    #pragma unroll
    for (int a = 0; a < 4; ++a)
        #pragma unroll
        for (int b = 0; b < 4; ++b)
            acc[a][b] = (floatx4){0.f, 0.f, 0.f, 0.f};

    const __hip_bfloat16* gA0 = Ab + (size_t)(i0 + srow) * N_NODES + skcol;
    const __hip_bfloat16* gB0 = Xt + (size_t)(j0 + srow) * N_NODES + skcol;

    for (int k0 = 0; k0 < N_NODES; k0 += 32) {
        __syncthreads();
        gload_lds16(gA0 + k0,                        As + w * 512);
        gload_lds16(gA0 + (size_t)64 * N_NODES + k0, As + 2048 + w * 512);
        gload_lds16(gB0 + k0,                        Bs + w * 512);
        gload_lds16(gB0 + (size_t)64 * N_NODES + k0, Bs + 2048 + w * 512);
        __syncthreads();
        short8 af[4], bfr[4];
        #pragma unroll
        for (int mt = 0; mt < 4; ++mt)
            af[mt] = *(const short8*)(As + (wm * 64 + mt * 16 + ar) * 32 + kq);
        #pragma unroll
        for (int nt = 0; nt < 4; ++nt)
            bfr[nt] = *(const short8*)(Bs + (wn * 64 + nt * 16 + ar) * 32 + kq);
        #pragma unroll
        for (int mt = 0; mt < 4; ++mt)
            #pragma unroll
            for (int nt = 0; nt < 4; ++nt)
                acc[mt][nt] = __builtin_amdgcn_mfma_f32_16x16x32_bf16(
                    af[mt], bfr[nt], acc[mt][nt], 0, 0, 0);
    }

    #pragma unroll
    for (int mt = 0; mt < 4; ++mt) {
        const int ibase = i0 + wm * 64 + mt * 16 + (l >> 4) * 4;
        #pragma unroll
        for (int nt = 0; nt < 4; ++nt) {
            const int j = j0 + wn * 64 + nt * 16 + (l & 15);
            const int bs = j >> 6, c = j & 63;
            #pragma unroll
            for (int r = 0; r < 4; ++r) {
                const int i = ibase + r;
                const size_t xi = ((size_t)bs * N_NODES + i) * CDIM + c;
                float g = x[xi] - dvec[i] * acc[mt][nt][r];
                G[xi] = __float2bfloat16(g);
            }
        }
    }
}

__global__ __launch_bounds__(256) void k_out(const __hip_bfloat16* __restrict__ G,
                                             const float* __restrict__ W,
                                             float* __restrict__ out) {
    __shared__ float Wt[64 * 132];
    __shared__ __hip_bfloat16 Gs[32 * 64];
    const int t = threadIdx.x;
    const int bs = blockIdx.y;
    const int i0 = blockIdx.x * 32;
    #pragma unroll
    for (int it = 0; it < 32; ++it) {
        int p = it * 256 + t;
        int h = p & 127, c = p >> 7;
        Wt[c * 132 + h] = W[h * 64 + c];
    }
    const short4* gp4 = (const short4*)(G + ((size_t)bs * N_NODES + i0) * CDIM);
    ((short4*)Gs)[t]       = gp4[t];
    ((short4*)Gs)[256 + t] = gp4[256 + t];
    __syncthreads();

    const int hg = t & 31;
    const int ig = t >> 5;
    float acc[4][4] = {};
    #pragma unroll
    for (int c = 0; c < 64; ++c) {
        float4 wv = *(const float4*)(Wt + c * 132 + hg * 4);
        #pragma unroll
        for (int ii = 0; ii < 4; ++ii) {
            float g = __bfloat162float(Gs[(ig * 4 + ii) * 64 + c]);
            acc[ii][0] += g * wv.x;
            acc[ii][1] += g * wv.y;
            acc[ii][2] += g * wv.z;
            acc[ii][3] += g * wv.w;
        }
    }
    #pragma unroll
    for (int ii = 0; ii < 4; ++ii) {
        const int i = i0 + ig * 4 + ii;
        float4 o;
        o.x = 1.f / (1.f + __expf(-acc[ii][0]));
        o.y = 1.f / (1.f + __expf(-acc[ii][1]));
        o.z = 1.f / (1.f + __expf(-acc[ii][2]));
        o.w = 1.f / (1.f + __expf(-acc[ii][3]));
        *(float4*)(out + ((size_t)bs * N_NODES + i) * HDIM + hg * 4) = o;
    }
}

extern "C" void kernel_launch(void* const* d_in, const int* in_sizes, int n_in,
                              void* d_out, int out_size, void* d_ws, size_t ws_size,
                              hipStream_t stream) {
    const float* x = (const float*)d_in[0];   // [48][4096][64]
    const float* A = (const float*)d_in[1];   // [4096][4096]
    const float* W = (const float*)d_in[2];   // [128][64]
    float* out  = (float*)d_out;              // out0: 25165824 floats
    float* outA = out + 25165824;             // A passthrough

    char* ws = (char*)d_ws;
    float* dvec = (float*)ws;
    const size_t offD = 16384;
    const size_t szAb = (size_t)16777216 * 2;     // 32 MB
    const size_t szXt = (size_t)3072 * 4096 * 2;  // 24 MB

    if (ws_size >= offD + szAb + szXt) {
        // fused path: Ab, Xt in workspace; no G intermediate
        __hip_bfloat16* Ab = (__hip_bfloat16*)(ws + offD);
        __hip_bfloat16* Xt = (__hip_bfloat16*)(ws + offD + szAb);
        k_prep    <<<4096, 256, 0, stream>>>(A, outA, Ab, dvec);
        k_buildXt <<<dim3(64, 48), 256, 0, stream>>>(x, dvec, Xt);
        k_gemm_out<<<256, 512, 0, stream>>>(Ab, Xt, x, dvec, W, out);
    } else {
        // legacy fallback: Ab in (dead) out0 region, G in ws
        __hip_bfloat16* Ab = (__hip_bfloat16*)out;
        __hip_bfloat16* Xt = (__hip_bfloat16*)(ws + offD);
        __hip_bfloat16* G  = (__hip_bfloat16*)(ws + offD + szXt);
        k_prep    <<<4096, 256, 0, stream>>>(A, outA, Ab, dvec);
        k_buildXt <<<dim3(64, 48), 256, 0, stream>>>(x, dvec, Xt);
        k_gemm    <<<dim3(24, 32), 256, 0, stream>>>(Ab, Xt, x, dvec, G);
        k_out     <<<dim3(128, 48), 256, 0, stream>>>(G, W, out);
    }
}